// Round 12
// baseline (274.213 us; speedup 1.0000x reference)
//
#include <hip/hip_runtime.h>
#include <math.h>

#define DD 128
#define NEG 0.01f
#define SCHUNK 4096

typedef __attribute__((ext_vector_type(8))) _Float16 half8;
typedef __attribute__((ext_vector_type(4))) float f32x4;

__device__ __forceinline__ float lrelu(float x){ return x > 0.f ? x : NEG * x; }

__device__ __forceinline__ unsigned short h2u(_Float16 h){
    union { _Float16 h; unsigned short u; } v; v.h = h; return v.u;
}
__device__ __forceinline__ _Float16 u2h(unsigned short u){
    union { unsigned short u; _Float16 h; } v; v.u = u; return v.h;
}

__device__ __forceinline__ half8 h8max(half8 x, half8 y){
#if __has_builtin(__builtin_elementwise_max)
    return __builtin_elementwise_max(x, y);
#else
    half8 r;
    #pragma unroll
    for (int i = 0; i < 8; i++) r[i] = x[i] > y[i] ? x[i] : y[i];
    return r;
#endif
}

// Launch-1 fusion: three disjoint block ranges.
//  [0,nhist):        histogram atomics, rank[i] = arrival index in dst bucket
//  [nhist,+npack):   fp16 pack of Wa1+Wout into wpack (B-fragment order)
//  [nhist+npack,..): node linear (lin2) with INLINE W fp32->fp16 transposed
//                    staging (coalesced float4 reads, scattered one-time LDS
//                    writes) — no wpack dependency, so lin2's MFMA work
//                    overlaps the atomic phase instead of waiting for scans.
__global__ __launch_bounds__(256) void hist_pack_lin2(
        const int* dst, int* deg, int* rank, int E, int nhist, int npack,
        const float* Wa1, const float* Wout, unsigned short* wpack,
        const float* X1, const float* W1, const float* b1,
        unsigned short* Yb1, int n1, int g1,
        const float* X2, const float* W2, const float* b2,
        unsigned short* Yb2, int n2){
    __shared__ unsigned short sB[16384];   // 32 KB (lin2 blocks only)
    const int tid = threadIdx.x;
    const int bid = blockIdx.x;
    if (bid < nhist){
        int i = bid * 256 + tid;
        if (i < E) rank[i] = atomicAdd(&deg[dst[i]], 1);
        return;
    }
    if (bid < nhist + npack){
        int i = (bid - nhist) * 256 + tid;   // [0, 2*16384)
        if (i < 2 * 16384){
            int seg = i >> 14, t = i & 16383;
            int j = t & 7, lane = (t >> 3) & 63, nt = (t >> 9) & 7, kc = t >> 12;
            int k = kc * 32 + (lane >> 4) * 8 + j;
            int n = nt * 16 + (lane & 15);
            const float* W = (seg == 0) ? Wa1 : Wout;
            wpack[i] = h2u((_Float16)W[k * DD + n]);
        }
        return;
    }
    const int lb = bid - nhist - npack;
    const int second = (lb >= g1);
    const float* X = second ? X2 : X1;
    const float* W = second ? W2 : W1;
    const float* b = second ? b2 : b1;
    unsigned short* Yb = second ? Yb2 : Yb1;
    const int nrows = second ? n2 : n1;
    const int bidx = second ? (lb - g1) : lb;
    // inline transposed staging: thread reads 8 contiguous fp32 (coalesced),
    // writes 8 scattered fp16 into B-fragment-order LDS. Same rounding as
    // the pack kernel ((_Float16) cast), so numerics identical.
    #pragma unroll
    for (int c = 0; c < 8; c++){
        int e = (c * 256 + tid) * 8;
        int k = e >> 7, n0 = e & 127;
        float4 v0 = *(const float4*)(W + e);
        float4 v1 = *(const float4*)(W + e + 4);
        float vv[8] = {v0.x, v0.y, v0.z, v0.w, v1.x, v1.y, v1.z, v1.w};
        int kc = k >> 5, jj = k & 7, lhi = (k >> 3) & 3;
        #pragma unroll
        for (int j = 0; j < 8; j++){
            int nn = n0 + j;
            int lane2 = (lhi << 4) | (nn & 15);
            int idx = (((((kc << 3) | (nn >> 4)) << 6) | lane2) << 3) | jj;
            sB[idx] = h2u((_Float16)vv[j]);
        }
    }
    const int wave = tid >> 6, lane = tid & 63;
    const int qd = lane >> 4, ln16 = lane & 15;
    const int row0 = bidx * 128 + wave * 32;
    int r0 = row0 + ln16;       if (r0 >= nrows) r0 = nrows - 1;
    int r1 = row0 + 16 + ln16;  if (r1 >= nrows) r1 = nrows - 1;
    f32x4 acc[2][8];
    #pragma unroll
    for (int rt = 0; rt < 2; rt++)
        #pragma unroll
        for (int nt = 0; nt < 8; nt++)
            acc[rt][nt] = (f32x4){0.f, 0.f, 0.f, 0.f};
    __syncthreads();
    #pragma unroll
    for (int kc = 0; kc < 4; kc++){
        const int koff = kc * 32 + qd * 8;
        half8 a[2];
        const float* px[2] = {X + (size_t)r0 * DD + koff, X + (size_t)r1 * DD + koff};
        #pragma unroll
        for (int rt = 0; rt < 2; rt++){
            float4 v0 = *(const float4*)(px[rt]);
            float4 v1 = *(const float4*)(px[rt] + 4);
            a[rt][0] = (_Float16)v0.x; a[rt][1] = (_Float16)v0.y;
            a[rt][2] = (_Float16)v0.z; a[rt][3] = (_Float16)v0.w;
            a[rt][4] = (_Float16)v1.x; a[rt][5] = (_Float16)v1.y;
            a[rt][6] = (_Float16)v1.z; a[rt][7] = (_Float16)v1.w;
        }
        #pragma unroll
        for (int nt = 0; nt < 8; nt++){
            const int fi = (((kc << 3) + nt) << 6 | lane) << 3;
            half8 bw = *(const half8*)&sB[fi];
            acc[0][nt] = __builtin_amdgcn_mfma_f32_16x16x32_f16(a[0], bw, acc[0][nt], 0, 0, 0);
            acc[1][nt] = __builtin_amdgcn_mfma_f32_16x16x32_f16(a[1], bw, acc[1][nt], 0, 0, 0);
        }
    }
    #pragma unroll
    for (int nt = 0; nt < 8; nt++){
        const int col = nt * 16 + ln16;
        const float bv = b[col];
        #pragma unroll
        for (int rt = 0; rt < 2; rt++){
            #pragma unroll
            for (int r = 0; r < 4; r++){
                int row = row0 + rt * 16 + qd * 4 + r;
                if (row < nrows){
                    float y = acc[rt][nt][r] + bv;
                    Yb[(size_t)row * DD + col] = h2u((_Float16)y);
                }
            }
        }
    }
}

// two-level scan, level 1: per-chunk sums (chunk = 4096 ints)
__global__ __launch_bounds__(1024) void scan1(const int* deg, int* part, int n){
    __shared__ int wsum[16];
    const int tid = threadIdx.x;
    const int lane = tid & 63, wid = tid >> 6;
    int i4 = blockIdx.x * SCHUNK + tid * 4;
    int4 v = make_int4(0, 0, 0, 0);
    if (i4 + 3 < n) v = *(const int4*)(deg + i4);
    else {
        if (i4 + 0 < n) v.x = deg[i4 + 0];
        if (i4 + 1 < n) v.y = deg[i4 + 1];
        if (i4 + 2 < n) v.z = deg[i4 + 2];
        if (i4 + 3 < n) v.w = deg[i4 + 3];
    }
    int t = v.x + v.y + v.z + v.w;
    #pragma unroll
    for (int off = 1; off < 64; off <<= 1) t += __shfl_xor(t, off, 64);
    if (lane == 0) wsum[wid] = t;
    __syncthreads();
    if (tid == 0){
        int s = 0;
        #pragma unroll
        for (int j = 0; j < 16; j++) s += wsum[j];
        part[blockIdx.x] = s;
    }
}

// two-level scan, level 2: exclusive offsets (row_off only)
__global__ __launch_bounds__(1024) void scan2(const int* deg, const int* part,
        int* row_off, int n, int nchunks){
    __shared__ int wsum[16];
    const int tid = threadIdx.x;
    const int lane = tid & 63, wid = tid >> 6;
    const int b = blockIdx.x;
    int carry = 0;
    for (int j = 0; j < b; j++) carry += part[j];
    int i4 = b * SCHUNK + tid * 4;
    int4 v = make_int4(0, 0, 0, 0);
    if (i4 + 3 < n) v = *(const int4*)(deg + i4);
    else {
        if (i4 + 0 < n) v.x = deg[i4 + 0];
        if (i4 + 1 < n) v.y = deg[i4 + 1];
        if (i4 + 2 < n) v.z = deg[i4 + 2];
        if (i4 + 3 < n) v.w = deg[i4 + 3];
    }
    int tsum = v.x + v.y + v.z + v.w;
    int x = tsum;
    #pragma unroll
    for (int off = 1; off < 64; off <<= 1){
        int t = __shfl_up(x, off, 64);
        if (lane >= off) x += t;
    }
    if (lane == 63) wsum[wid] = x;
    __syncthreads();
    int wprefix = 0;
    #pragma unroll
    for (int j = 0; j < 16; j++) if (j < wid) wprefix += wsum[j];
    int excl = carry + wprefix + (x - tsum);
    if (i4 + 3 < n){
        int4 o;
        o.x = excl; o.y = excl + v.x; o.z = o.y + v.y; o.w = o.z + v.z;
        *(int4*)(row_off + i4) = o;
    } else {
        int a = excl;
        if (i4 + 0 < n){ row_off[i4 + 0] = a; a += v.x; }
        if (i4 + 1 < n){ row_off[i4 + 1] = a; a += v.y; }
        if (i4 + 2 < n){ row_off[i4 + 2] = a; a += v.z; }
        if (i4 + 3 < n){ row_off[i4 + 3] = a; }
    }
    if (b == 0 && tid == 0){
        int tot = 0;
        for (int j = 0; j < nchunks; j++) tot += part[j];
        row_off[n] = tot;
    }
}

// atomic-free scatter of PACKED pairs (dst<<16 | src; both < 2^16 here)
__global__ void scatter_pack(const int* src, const int* dst, const int* row_off,
                             const int* rank, unsigned int* pairs, int E){
    int i = blockIdx.x * blockDim.x + threadIdx.x;
    if (i < E){
        unsigned int d = (unsigned int)dst[i];
        pairs[row_off[d] + rank[i]] = (d << 16) | (unsigned int)src[i];
    }
}

// A-fragment: 8 fp16 of lrelu(hs_row + hd_row) — packed fp16 math.
__device__ __forceinline__ half8 afrag_from(half8 a, half8 b){
    half8 s = a + b;
    return h8max(s, s * (_Float16)NEG);
}

// MFMA edge attention score on SORTED edges; 256 edges/block (8 waves).
// Best-measured structure: rt-serialized, b_a1 folded into acc init, lrelu
// via v_max, __expf. exp() without +b2: per-node e^b2 cancels in alpha.
// Bijective XCD swizzle on blockIdx (m204). Packed pairs.
__global__ __launch_bounds__(512) void edge_score_mfma(
        const unsigned short* hs_h, const unsigned short* hd_h,
        const unsigned int* pairs,
        const unsigned short* wa1p, const float* ba1,
        const float* Wa2, const float* ba2,
        float* s_w, int E){
    __shared__ unsigned short sB[16384];  // 32 KB
    const int tid = threadIdx.x;
    {
        const uint4* g = (const uint4*)wa1p;
        uint4* l = (uint4*)sB;
        #pragma unroll
        for (int t = 0; t < 4; t++) l[tid + 512 * t] = g[tid + 512 * t];
    }
    // bijective XCD-chunked block remap (works for any gridDim.x)
    int nblk = gridDim.x;
    int q = nblk >> 3, r = nblk & 7;
    int x = blockIdx.x & 7, y = blockIdx.x >> 3;
    int bswz = (x < r ? x * (q + 1) : r * (q + 1) + (x - r) * q) + y;
    const int wave = tid >> 6, lane = tid & 63;
    const int qd = lane >> 4, ln16 = lane & 15;
    const int e0 = bswz * 256 + wave * 32;
    float b1v[8], w2v[8];
    #pragma unroll
    for (int nt = 0; nt < 8; nt++){
        b1v[nt] = ba1[nt * 16 + ln16];
        w2v[nt] = Wa2[nt * 16 + ln16];
    }
    __syncthreads();
    for (int rt = 0; rt < 2; rt++){
        int eid = e0 + rt * 16 + ln16;
        if (eid >= E) eid = E - 1;
        const unsigned int pp = pairs[eid];
        const unsigned int si = pp & 0xffffu, di = pp >> 16;
        f32x4 acc[8];
        #pragma unroll
        for (int nt = 0; nt < 8; nt++)
            acc[nt] = (f32x4){b1v[nt], b1v[nt], b1v[nt], b1v[nt]};
        #pragma unroll
        for (int kc = 0; kc < 4; kc++){
            const int koff = kc * 32 + qd * 8;
            half8 af = afrag_from(*(const half8*)(hs_h + (size_t)si * DD + koff),
                                  *(const half8*)(hd_h + (size_t)di * DD + koff));
            #pragma unroll
            for (int nt = 0; nt < 8; nt++){
                half8 bf = *(const half8*)&sB[(((kc << 3) + nt) << 6 | lane) << 3];
                acc[nt] = __builtin_amdgcn_mfma_f32_16x16x32_f16(af, bf, acc[nt], 0, 0, 0);
            }
        }
        float p[4] = {0.f, 0.f, 0.f, 0.f};
        #pragma unroll
        for (int nt = 0; nt < 8; nt++)
            #pragma unroll
            for (int r2 = 0; r2 < 4; r2++){
                float z = acc[nt][r2];
                z = fmaxf(z, NEG * z);      // lrelu via v_max_f32
                p[r2] += z * w2v[nt];
            }
        #pragma unroll
        for (int r2 = 0; r2 < 4; r2++){
            float v = p[r2];
            #pragma unroll
            for (int off = 1; off < 16; off <<= 1) v += __shfl_xor(v, off, 64);
            p[r2] = __expf(v);
        }
        if (ln16 == 0){
            int row = e0 + rt * 16 + qd * 4;
            #pragma unroll
            for (int r2 = 0; r2 < 4; r2++)
                if (row + r2 < E) s_w[row + r2] = p[r2];
        }
    }
}

// Fused aggregation + final linear. 8 waves/block, one dst node per wave.
// Main loop software-pipelined: next iteration's pairs/s_w loads issue
// under the current iteration's row gathers (breaks the cross-iteration
// pairs->gather->FMA dependent chain).
__global__ __launch_bounds__(512) void agg_lin(
        const unsigned short* hs_h, const unsigned short* hd_h,
        const int* row_off, const unsigned int* pairs, const float* s_w,
        const unsigned short* wout, const float* bout,
        float* Y, int n_dst){
    __shared__ unsigned short sB[16384];   // 32 KB W_out (B-fragment order)
    __shared__ unsigned short rbuf[2048];  // 16 rows x 128 fp16, XOR-swizzled
    const int tid = threadIdx.x;
    {
        const uint4* g = (const uint4*)wout;
        uint4* l = (uint4*)sB;
        #pragma unroll
        for (int t = 0; t < 4; t++) l[tid + 512 * t] = g[tid + 512 * t];
    }
    const int wave = tid >> 6, lane = tid & 63;
    const int w = blockIdx.x * 8 + wave;
    const int hf = lane >> 5, l32 = lane & 31;
    int beg = 0, end = 0;
    if (w < n_dst){ beg = row_off[w]; end = row_off[w + 1]; }
    float4 acc = make_float4(0.f, 0.f, 0.f, 0.f);
    float sa = 0.f;
    int e = beg;
    int rows[4]; float wv[4];
    if (e + 7 < end){
        #pragma unroll
        for (int j = 0; j < 4; j++){
            int ee = e + 2 * j + hf;
            rows[j] = (int)(pairs[ee] & 0xffffu);
            wv[j] = s_w[ee];
        }
    }
    while (e + 7 < end){
        ushort4 uv[4];
        #pragma unroll
        for (int j = 0; j < 4; j++)
            uv[j] = *(const ushort4*)(hs_h + (size_t)rows[j] * DD + l32 * 4);
        const int en = e + 8;
        int nrows[4]; float nwv[4];
        const bool more = (en + 7 < end);
        if (more){
            #pragma unroll
            for (int j = 0; j < 4; j++){
                int ee = en + 2 * j + hf;
                nrows[j] = (int)(pairs[ee] & 0xffffu);
                nwv[j] = s_w[ee];
            }
        }
        #pragma unroll
        for (int j = 0; j < 4; j++){
            acc.x += wv[j] * (float)u2h(uv[j].x);
            acc.y += wv[j] * (float)u2h(uv[j].y);
            acc.z += wv[j] * (float)u2h(uv[j].z);
            acc.w += wv[j] * (float)u2h(uv[j].w);
            sa += wv[j];
        }
        e = en;
        if (more){
            #pragma unroll
            for (int j = 0; j < 4; j++){ rows[j] = nrows[j]; wv[j] = nwv[j]; }
        }
    }
    for (; e < end; e += 4){
        // two edges per half-wave, clamped index + masked weight
        int ee0 = e + hf;          int ee1 = e + 2 + hf;
        int ec0 = ee0 < end ? ee0 : end - 1;
        int ec1 = ee1 < end ? ee1 : end - 1;
        int r0 = (int)(pairs[ec0] & 0xffffu), r1 = (int)(pairs[ec1] & 0xffffu);
        float wv0 = (ee0 < end) ? s_w[ec0] : 0.f;
        float wv1 = (ee1 < end) ? s_w[ec1] : 0.f;
        ushort4 u0 = *(const ushort4*)(hs_h + (size_t)r0 * DD + l32 * 4);
        ushort4 u1 = *(const ushort4*)(hs_h + (size_t)r1 * DD + l32 * 4);
        acc.x += wv0 * (float)u2h(u0.x) + wv1 * (float)u2h(u1.x);
        acc.y += wv0 * (float)u2h(u0.y) + wv1 * (float)u2h(u1.y);
        acc.z += wv0 * (float)u2h(u0.z) + wv1 * (float)u2h(u1.z);
        acc.w += wv0 * (float)u2h(u0.w) + wv1 * (float)u2h(u1.w);
        sa += wv0 + wv1;
    }
    // combine the two half-wave partials (same dims, disjoint edges)
    acc.x += __shfl_xor(acc.x, 32, 64);
    acc.y += __shfl_xor(acc.y, 32, 64);
    acc.z += __shfl_xor(acc.z, 32, 64);
    acc.w += __shfl_xor(acc.w, 32, 64);
    sa    += __shfl_xor(sa, 32, 64);
    const float inv = (end > beg) ? 1.f / sa : 0.f;
    if (hf == 0 && w < n_dst){
        float hx = 0.f, hy = 0.f, hz = 0.f, hw = 0.f;
        if (end > beg){
            ushort4 hu = *(const ushort4*)(hd_h + (size_t)w * DD + l32 * 4);
            hx = (float)u2h(hu.x); hy = (float)u2h(hu.y);
            hz = (float)u2h(hu.z); hw = (float)u2h(hu.w);
        }
        ushort4 hv;
        hv.x = h2u((_Float16)(acc.x * inv + hx));
        hv.y = h2u((_Float16)(acc.y * inv + hy));
        hv.z = h2u((_Float16)(acc.z * inv + hz));
        hv.w = h2u((_Float16)(acc.w * inv + hw));
        // row = wave, dims l32*4..+3 -> byte l32*8, XOR-swizzled per row
        int wb = wave * 256 + ((l32 * 8) ^ ((wave & 7) << 4));
        *(ushort4*)((char*)rbuf + wb) = hv;
    }
    __syncthreads();
    // Phase 2: wave = nt column tile; A rows 8-15 garbage (discarded rows).
    {
        const int nt = wave;
        const int qd = lane >> 4, ln16 = lane & 15;
        f32x4 c = (f32x4){0.f, 0.f, 0.f, 0.f};
        #pragma unroll
        for (int kc = 0; kc < 4; kc++){
            int rb = ln16 * 256 + ((kc * 64 + qd * 16) ^ ((ln16 & 7) << 4));
            half8 af = *(const half8*)((const char*)rbuf + rb);
            half8 bf = *(const half8*)&sB[(((kc << 3) + nt) << 6 | lane) << 3];
            c = __builtin_amdgcn_mfma_f32_16x16x32_f16(af, bf, c, 0, 0, 0);
        }
        const int col = nt * 16 + ln16;
        const float bv = bout[col];
        #pragma unroll
        for (int r = 0; r < 4; r++){
            int row = qd * 4 + r;
            int node = blockIdx.x * 8 + row;
            if (row < 8 && node < n_dst){
                float y = c[r] + bv;
                Y[(size_t)node * DD + col] = lrelu(y);
            }
        }
    }
}

extern "C" void kernel_launch(void* const* d_in, const int* in_sizes, int n_in,
                              void* d_out, int out_size, void* d_ws, size_t ws_size,
                              hipStream_t stream){
    const float* feat_src = (const float*)d_in[0];
    const float* feat_dst = (const float*)d_in[1];
    const int*   src_idx  = (const int*)d_in[2];
    const int*   dst_idx  = (const int*)d_in[3];
    const float* W_src = (const float*)d_in[4];
    const float* b_src = (const float*)d_in[5];
    const float* W_dst = (const float*)d_in[6];
    const float* b_dst = (const float*)d_in[7];
    const float* W_a1  = (const float*)d_in[8];
    const float* b_a1  = (const float*)d_in[9];
    const float* W_a2  = (const float*)d_in[10];
    const float* b_a2  = (const float*)d_in[11];
    const float* W_out = (const float*)d_in[12];
    const float* b_out = (const float*)d_in[13];
    const int n_src = in_sizes[0] / DD;
    const int n_dst = in_sizes[1] / DD;
    const int E = in_sizes[2];
    const int nchunks = (n_dst + SCHUNK - 1) / SCHUNK;

    // workspace layout (all 16B-aligned segments)
    char* p = (char*)d_ws;
    unsigned short* hs_h = (unsigned short*)p;  p += (size_t)n_src * DD * 2;
    unsigned short* hd_h = (unsigned short*)p;  p += (size_t)n_dst * DD * 2;
    unsigned short* wpack = (unsigned short*)p; p += 2 * 16384 * 2;
    float* s_w = (float*)p;                     p += (size_t)E * 4;
    unsigned int* pairs = (unsigned int*)p;     p += (size_t)E * 4;
    int* rank = (int*)p;                        p += (size_t)E * 4;
    int* deg = (int*)p;                         p += (size_t)n_dst * 4;
    int* part = (int*)p;                        p += 64 * 4;
    int* row_off = (int*)p;                     p += ((size_t)n_dst + 1) * 4;
    float* nf = (float*)d_out;

    const unsigned short* wa1p = wpack;
    const unsigned short* wout = wpack + 16384;

    hipMemsetAsync(deg, 0, (size_t)n_dst * 4, stream);
    const int nhist = (E + 255) / 256;
    const int npack = (2 * 16384 + 255) / 256;
    const int g1 = (n_src + 127) / 128;
    const int g2 = (n_dst + 127) / 128;
    hist_pack_lin2<<<nhist + npack + g1 + g2, 256, 0, stream>>>(
        dst_idx, deg, rank, E, nhist, npack,
        W_a1, W_out, wpack,
        feat_src, W_src, b_src, hs_h, n_src, g1,
        feat_dst, W_dst, b_dst, hd_h, n_dst);
    scan1<<<nchunks, 1024, 0, stream>>>(deg, part, n_dst);
    scan2<<<nchunks, 1024, 0, stream>>>(deg, part, row_off, n_dst, nchunks);
    scatter_pack<<<(E + 255) / 256, 256, 0, stream>>>(src_idx, dst_idx, row_off,
                                                      rank, pairs, E);
    edge_score_mfma<<<(E + 255) / 256, 512, 0, stream>>>(hs_h, hd_h, pairs, wa1p, b_a1,
                                                         W_a2, b_a2, s_w, E);
    agg_lin<<<(n_dst + 7) / 8, 512, 0, stream>>>(hs_h, hd_h, row_off, pairs, s_w,
                                                 wout, b_out, nf, n_dst);
}

// Round 13
// 266.733 us; speedup vs baseline: 1.0280x; 1.0280x over previous
//
#include <hip/hip_runtime.h>
#include <math.h>

#define DD 128
#define NEG 0.01f
#define SCHUNK 4096

typedef __attribute__((ext_vector_type(8))) _Float16 half8;
typedef __attribute__((ext_vector_type(4))) float f32x4;

__device__ __forceinline__ float lrelu(float x){ return x > 0.f ? x : NEG * x; }

__device__ __forceinline__ unsigned short h2u(_Float16 h){
    union { _Float16 h; unsigned short u; } v; v.h = h; return v.u;
}
__device__ __forceinline__ _Float16 u2h(unsigned short u){
    union { unsigned short u; _Float16 h; } v; v.u = u; return v.h;
}

__device__ __forceinline__ half8 h8max(half8 x, half8 y){
#if __has_builtin(__builtin_elementwise_max)
    return __builtin_elementwise_max(x, y);
#else
    half8 r;
    #pragma unroll
    for (int i = 0; i < 8; i++) r[i] = x[i] > y[i] ? x[i] : y[i];
    return r;
#endif
}

// bijective XCD-chunked block remap (m204): contiguous chunks per XCD
__device__ __forceinline__ int xcd_swz(int bid, int nblk){
    int q = nblk >> 3, r = nblk & 7;
    int x = bid & 7, y = bid >> 3;
    return (x < r ? x * (q + 1) : r * (q + 1) + (x - r) * q) + y;
}

// histogram (returning per-edge rank) + fp16 weight pack fused.
// rank[i] = this edge's arrival index within its dst bucket -> scatter needs
// no atomics. wpack segs: 0 Wa1, 1 Wsrc, 2 Wdst, 3 Wout (B-fragment order).
__global__ void hist_pack(const int* dst, int* deg, int* rank, int E, int nhist,
                          const float* Wa1, const float* Wsrc,
                          const float* Wdst, const float* Wout,
                          unsigned short* wpack){
    const int bid = blockIdx.x;
    if (bid < nhist){
        int i = bid * 256 + threadIdx.x;
        if (i < E) rank[i] = atomicAdd(&deg[dst[i]], 1);
    } else {
        int i = (bid - nhist) * 256 + threadIdx.x;   // [0, 4*16384)
        if (i >= 4 * 16384) return;
        int seg = i >> 14, t = i & 16383;
        int j = t & 7, lane = (t >> 3) & 63, nt = (t >> 9) & 7, kc = t >> 12;
        int k = kc * 32 + (lane >> 4) * 8 + j;
        int n = nt * 16 + (lane & 15);
        const float* W = (seg == 0) ? Wa1 : (seg == 1) ? Wsrc : (seg == 2) ? Wdst : Wout;
        wpack[i] = h2u((_Float16)W[k * DD + n]);
    }
}

// two-level scan, level 1: per-chunk sums (chunk = 4096 ints)
__global__ __launch_bounds__(1024) void scan1(const int* deg, int* part, int n){
    __shared__ int wsum[16];
    const int tid = threadIdx.x;
    const int lane = tid & 63, wid = tid >> 6;
    int i4 = blockIdx.x * SCHUNK + tid * 4;
    int4 v = make_int4(0, 0, 0, 0);
    if (i4 + 3 < n) v = *(const int4*)(deg + i4);
    else {
        if (i4 + 0 < n) v.x = deg[i4 + 0];
        if (i4 + 1 < n) v.y = deg[i4 + 1];
        if (i4 + 2 < n) v.z = deg[i4 + 2];
        if (i4 + 3 < n) v.w = deg[i4 + 3];
    }
    int t = v.x + v.y + v.z + v.w;
    #pragma unroll
    for (int off = 1; off < 64; off <<= 1) t += __shfl_xor(t, off, 64);
    if (lane == 0) wsum[wid] = t;
    __syncthreads();
    if (tid == 0){
        int s = 0;
        #pragma unroll
        for (int j = 0; j < 16; j++) s += wsum[j];
        part[blockIdx.x] = s;
    }
}

// two-level scan, level 2: exclusive offsets (row_off only)
__global__ __launch_bounds__(1024) void scan2(const int* deg, const int* part,
        int* row_off, int n, int nchunks){
    __shared__ int wsum[16];
    const int tid = threadIdx.x;
    const int lane = tid & 63, wid = tid >> 6;
    const int b = blockIdx.x;
    int carry = 0;
    for (int j = 0; j < b; j++) carry += part[j];
    int i4 = b * SCHUNK + tid * 4;
    int4 v = make_int4(0, 0, 0, 0);
    if (i4 + 3 < n) v = *(const int4*)(deg + i4);
    else {
        if (i4 + 0 < n) v.x = deg[i4 + 0];
        if (i4 + 1 < n) v.y = deg[i4 + 1];
        if (i4 + 2 < n) v.z = deg[i4 + 2];
        if (i4 + 3 < n) v.w = deg[i4 + 3];
    }
    int tsum = v.x + v.y + v.z + v.w;
    int x = tsum;
    #pragma unroll
    for (int off = 1; off < 64; off <<= 1){
        int t = __shfl_up(x, off, 64);
        if (lane >= off) x += t;
    }
    if (lane == 63) wsum[wid] = x;
    __syncthreads();
    int wprefix = 0;
    #pragma unroll
    for (int j = 0; j < 16; j++) if (j < wid) wprefix += wsum[j];
    int excl = carry + wprefix + (x - tsum);
    if (i4 + 3 < n){
        int4 o;
        o.x = excl; o.y = excl + v.x; o.z = o.y + v.y; o.w = o.z + v.z;
        *(int4*)(row_off + i4) = o;
    } else {
        int a = excl;
        if (i4 + 0 < n){ row_off[i4 + 0] = a; a += v.x; }
        if (i4 + 1 < n){ row_off[i4 + 1] = a; a += v.y; }
        if (i4 + 2 < n){ row_off[i4 + 2] = a; a += v.z; }
        if (i4 + 3 < n){ row_off[i4 + 3] = a; }
    }
    if (b == 0 && tid == 0){
        int tot = 0;
        for (int j = 0; j < nchunks; j++) tot += part[j];
        row_off[n] = tot;
    }
}

// Fused: blocks [0,nsc): atomic-free scatter of PACKED pairs
// (dst<<16 | src — both < 2^16 for this problem size); 4B random write.
// blocks [nsc,..): node linear via fp16 MFMA (two inputs, disjoint ranges).
__global__ __launch_bounds__(256) void scatter_lin2(
        const int* src, const int* dst, const int* row_off, const int* rank,
        unsigned int* pairs, int E, int nsc,
        const float* X1, const unsigned short* W1, const float* b1,
        unsigned short* Yb1, int n1, int g1,
        const float* X2, const unsigned short* W2, const float* b2,
        unsigned short* Yb2, int n2){
    __shared__ unsigned short sB[16384];   // 32 KB (lin2 blocks only)
    const int tid = threadIdx.x;
    if (blockIdx.x < nsc){
        int i = blockIdx.x * 256 + tid;
        if (i < E){
            unsigned int d = (unsigned int)dst[i];
            unsigned int s = (unsigned int)src[i];
            pairs[row_off[d] + rank[i]] = (d << 16) | s;
        }
        return;
    }
    const int lb = blockIdx.x - nsc;
    const int second = (lb >= g1);
    const float* X = second ? X2 : X1;
    const unsigned short* W = second ? W2 : W1;
    const float* b = second ? b2 : b1;
    unsigned short* Yb = second ? Yb2 : Yb1;
    const int nrows = second ? n2 : n1;
    const int bidx = second ? (lb - g1) : lb;
    {
        const uint4* g = (const uint4*)W;
        uint4* l = (uint4*)sB;
        #pragma unroll
        for (int t = 0; t < 8; t++) l[tid + 256 * t] = g[tid + 256 * t];
    }
    const int wave = tid >> 6, lane = tid & 63;
    const int qd = lane >> 4, ln16 = lane & 15;
    const int row0 = bidx * 128 + wave * 32;
    int r0 = row0 + ln16;       if (r0 >= nrows) r0 = nrows - 1;
    int r1 = row0 + 16 + ln16;  if (r1 >= nrows) r1 = nrows - 1;
    f32x4 acc[2][8];
    #pragma unroll
    for (int rt = 0; rt < 2; rt++)
        #pragma unroll
        for (int nt = 0; nt < 8; nt++)
            acc[rt][nt] = (f32x4){0.f, 0.f, 0.f, 0.f};
    __syncthreads();
    #pragma unroll
    for (int kc = 0; kc < 4; kc++){
        const int koff = kc * 32 + qd * 8;
        half8 a[2];
        const float* px[2] = {X + (size_t)r0 * DD + koff, X + (size_t)r1 * DD + koff};
        #pragma unroll
        for (int rt = 0; rt < 2; rt++){
            float4 v0 = *(const float4*)(px[rt]);
            float4 v1 = *(const float4*)(px[rt] + 4);
            a[rt][0] = (_Float16)v0.x; a[rt][1] = (_Float16)v0.y;
            a[rt][2] = (_Float16)v0.z; a[rt][3] = (_Float16)v0.w;
            a[rt][4] = (_Float16)v1.x; a[rt][5] = (_Float16)v1.y;
            a[rt][6] = (_Float16)v1.z; a[rt][7] = (_Float16)v1.w;
        }
        #pragma unroll
        for (int nt = 0; nt < 8; nt++){
            const int fi = (((kc << 3) + nt) << 6 | lane) << 3;
            half8 bw = *(const half8*)&sB[fi];
            acc[0][nt] = __builtin_amdgcn_mfma_f32_16x16x32_f16(a[0], bw, acc[0][nt], 0, 0, 0);
            acc[1][nt] = __builtin_amdgcn_mfma_f32_16x16x32_f16(a[1], bw, acc[1][nt], 0, 0, 0);
        }
    }
    #pragma unroll
    for (int nt = 0; nt < 8; nt++){
        const int col = nt * 16 + ln16;
        const float bv = b[col];
        #pragma unroll
        for (int rt = 0; rt < 2; rt++){
            #pragma unroll
            for (int r = 0; r < 4; r++){
                int row = row0 + rt * 16 + qd * 4 + r;
                if (row < nrows){
                    float y = acc[rt][nt][r] + bv;
                    Yb[(size_t)row * DD + col] = h2u((_Float16)y);
                }
            }
        }
    }
}

// A-fragment: 8 fp16 of lrelu(hs_row + hd_row) — packed fp16 math.
__device__ __forceinline__ half8 afrag_from(half8 a, half8 b){
    half8 s = a + b;
    return h8max(s, s * (_Float16)NEG);
}

// MFMA edge attention score on SORTED edges; 256 edges/block (8 waves).
// Best-measured structure: rt-serialized, b_a1 folded into acc init, lrelu
// via v_max, __expf. exp() without +b2: per-node e^b2 cancels in alpha.
// Bijective XCD swizzle on blockIdx. Packed pairs: src=p&0xffff, dst=p>>16.
__global__ __launch_bounds__(512) void edge_score_mfma(
        const unsigned short* hs_h, const unsigned short* hd_h,
        const unsigned int* pairs,
        const unsigned short* wa1p, const float* ba1,
        const float* Wa2, const float* ba2,
        float* s_w, int E){
    __shared__ unsigned short sB[16384];  // 32 KB
    const int tid = threadIdx.x;
    {
        const uint4* g = (const uint4*)wa1p;
        uint4* l = (uint4*)sB;
        #pragma unroll
        for (int t = 0; t < 4; t++) l[tid + 512 * t] = g[tid + 512 * t];
    }
    int bswz = xcd_swz(blockIdx.x, gridDim.x);
    const int wave = tid >> 6, lane = tid & 63;
    const int qd = lane >> 4, ln16 = lane & 15;
    const int e0 = bswz * 256 + wave * 32;
    float b1v[8], w2v[8];
    #pragma unroll
    for (int nt = 0; nt < 8; nt++){
        b1v[nt] = ba1[nt * 16 + ln16];
        w2v[nt] = Wa2[nt * 16 + ln16];
    }
    __syncthreads();
    for (int rt = 0; rt < 2; rt++){
        int eid = e0 + rt * 16 + ln16;
        if (eid >= E) eid = E - 1;
        const unsigned int pp = pairs[eid];
        const unsigned int si = pp & 0xffffu, di = pp >> 16;
        f32x4 acc[8];
        #pragma unroll
        for (int nt = 0; nt < 8; nt++)
            acc[nt] = (f32x4){b1v[nt], b1v[nt], b1v[nt], b1v[nt]};
        #pragma unroll
        for (int kc = 0; kc < 4; kc++){
            const int koff = kc * 32 + qd * 8;
            half8 af = afrag_from(*(const half8*)(hs_h + (size_t)si * DD + koff),
                                  *(const half8*)(hd_h + (size_t)di * DD + koff));
            #pragma unroll
            for (int nt = 0; nt < 8; nt++){
                half8 bf = *(const half8*)&sB[(((kc << 3) + nt) << 6 | lane) << 3];
                acc[nt] = __builtin_amdgcn_mfma_f32_16x16x32_f16(af, bf, acc[nt], 0, 0, 0);
            }
        }
        float p[4] = {0.f, 0.f, 0.f, 0.f};
        #pragma unroll
        for (int nt = 0; nt < 8; nt++)
            #pragma unroll
            for (int r2 = 0; r2 < 4; r2++){
                float z = acc[nt][r2];
                z = fmaxf(z, NEG * z);      // lrelu via v_max_f32
                p[r2] += z * w2v[nt];
            }
        #pragma unroll
        for (int r2 = 0; r2 < 4; r2++){
            float v = p[r2];
            #pragma unroll
            for (int off = 1; off < 16; off <<= 1) v += __shfl_xor(v, off, 64);
            p[r2] = __expf(v);
        }
        if (ln16 == 0){
            int row = e0 + rt * 16 + qd * 4;
            #pragma unroll
            for (int r2 = 0; r2 < 4; r2++)
                if (row + r2 < E) s_w[row + r2] = p[r2];
        }
    }
}

// Fused aggregation + final linear. 8 waves/block, one dst node per wave.
// Main loop software-pipelined (next iter's pairs/s_w under current gathers).
// Bijective XCD swizzle: contiguous node chunks per XCD -> contiguous
// pairs/s_w/hd/Y streams per XCD L2 (hs gather random regardless).
__global__ __launch_bounds__(512) void agg_lin(
        const unsigned short* hs_h, const unsigned short* hd_h,
        const int* row_off, const unsigned int* pairs, const float* s_w,
        const unsigned short* wout, const float* bout,
        float* Y, int n_dst){
    __shared__ unsigned short sB[16384];   // 32 KB W_out (B-fragment order)
    __shared__ unsigned short rbuf[2048];  // 16 rows x 128 fp16, XOR-swizzled
    const int tid = threadIdx.x;
    {
        const uint4* g = (const uint4*)wout;
        uint4* l = (uint4*)sB;
        #pragma unroll
        for (int t = 0; t < 4; t++) l[tid + 512 * t] = g[tid + 512 * t];
    }
    int bswz = xcd_swz(blockIdx.x, gridDim.x);
    const int wave = tid >> 6, lane = tid & 63;
    const int w = bswz * 8 + wave;
    const int hf = lane >> 5, l32 = lane & 31;
    int beg = 0, end = 0;
    if (w < n_dst){ beg = row_off[w]; end = row_off[w + 1]; }
    float4 acc = make_float4(0.f, 0.f, 0.f, 0.f);
    float sa = 0.f;
    int e = beg;
    int rows[4]; float wv[4];
    if (e + 7 < end){
        #pragma unroll
        for (int j = 0; j < 4; j++){
            int ee = e + 2 * j + hf;
            rows[j] = (int)(pairs[ee] & 0xffffu);
            wv[j] = s_w[ee];
        }
    }
    while (e + 7 < end){
        ushort4 uv[4];
        #pragma unroll
        for (int j = 0; j < 4; j++)
            uv[j] = *(const ushort4*)(hs_h + (size_t)rows[j] * DD + l32 * 4);
        const int en = e + 8;
        int nrows[4]; float nwv[4];
        const bool more = (en + 7 < end);
        if (more){
            #pragma unroll
            for (int j = 0; j < 4; j++){
                int ee = en + 2 * j + hf;
                nrows[j] = (int)(pairs[ee] & 0xffffu);
                nwv[j] = s_w[ee];
            }
        }
        #pragma unroll
        for (int j = 0; j < 4; j++){
            acc.x += wv[j] * (float)u2h(uv[j].x);
            acc.y += wv[j] * (float)u2h(uv[j].y);
            acc.z += wv[j] * (float)u2h(uv[j].z);
            acc.w += wv[j] * (float)u2h(uv[j].w);
            sa += wv[j];
        }
        e = en;
        if (more){
            #pragma unroll
            for (int j = 0; j < 4; j++){ rows[j] = nrows[j]; wv[j] = nwv[j]; }
        }
    }
    for (; e < end; e += 4){
        // two edges per half-wave, clamped index + masked weight
        int ee0 = e + hf;          int ee1 = e + 2 + hf;
        int ec0 = ee0 < end ? ee0 : end - 1;
        int ec1 = ee1 < end ? ee1 : end - 1;
        int r0 = (int)(pairs[ec0] & 0xffffu), r1 = (int)(pairs[ec1] & 0xffffu);
        float wv0 = (ee0 < end) ? s_w[ec0] : 0.f;
        float wv1 = (ee1 < end) ? s_w[ec1] : 0.f;
        ushort4 u0 = *(const ushort4*)(hs_h + (size_t)r0 * DD + l32 * 4);
        ushort4 u1 = *(const ushort4*)(hs_h + (size_t)r1 * DD + l32 * 4);
        acc.x += wv0 * (float)u2h(u0.x) + wv1 * (float)u2h(u1.x);
        acc.y += wv0 * (float)u2h(u0.y) + wv1 * (float)u2h(u1.y);
        acc.z += wv0 * (float)u2h(u0.z) + wv1 * (float)u2h(u1.z);
        acc.w += wv0 * (float)u2h(u0.w) + wv1 * (float)u2h(u1.w);
        sa += wv0 + wv1;
    }
    // combine the two half-wave partials (same dims, disjoint edges)
    acc.x += __shfl_xor(acc.x, 32, 64);
    acc.y += __shfl_xor(acc.y, 32, 64);
    acc.z += __shfl_xor(acc.z, 32, 64);
    acc.w += __shfl_xor(acc.w, 32, 64);
    sa    += __shfl_xor(sa, 32, 64);
    const float inv = (end > beg) ? 1.f / sa : 0.f;
    if (hf == 0 && w < n_dst){
        float hx = 0.f, hy = 0.f, hz = 0.f, hw = 0.f;
        if (end > beg){
            ushort4 hu = *(const ushort4*)(hd_h + (size_t)w * DD + l32 * 4);
            hx = (float)u2h(hu.x); hy = (float)u2h(hu.y);
            hz = (float)u2h(hu.z); hw = (float)u2h(hu.w);
        }
        ushort4 hv;
        hv.x = h2u((_Float16)(acc.x * inv + hx));
        hv.y = h2u((_Float16)(acc.y * inv + hy));
        hv.z = h2u((_Float16)(acc.z * inv + hz));
        hv.w = h2u((_Float16)(acc.w * inv + hw));
        // row = wave, dims l32*4..+3 -> byte l32*8, XOR-swizzled per row
        int wb = wave * 256 + ((l32 * 8) ^ ((wave & 7) << 4));
        *(ushort4*)((char*)rbuf + wb) = hv;
    }
    __syncthreads();
    // Phase 2: wave = nt column tile; A rows 8-15 garbage (discarded rows).
    {
        const int nt = wave;
        const int qd = lane >> 4, ln16 = lane & 15;
        f32x4 c = (f32x4){0.f, 0.f, 0.f, 0.f};
        #pragma unroll
        for (int kc = 0; kc < 4; kc++){
            int rb = ln16 * 256 + ((kc * 64 + qd * 16) ^ ((ln16 & 7) << 4));
            half8 af = *(const half8*)((const char*)rbuf + rb);
            half8 bf = *(const half8*)&sB[(((kc << 3) + nt) << 6 | lane) << 3];
            c = __builtin_amdgcn_mfma_f32_16x16x32_f16(af, bf, c, 0, 0, 0);
        }
        const int col = nt * 16 + ln16;
        const float bv = bout[col];
        #pragma unroll
        for (int r = 0; r < 4; r++){
            int row = qd * 4 + r;
            int node = bswz * 8 + row;
            if (row < 8 && node < n_dst){
                float y = c[r] + bv;
                Y[(size_t)node * DD + col] = lrelu(y);
            }
        }
    }
}

extern "C" void kernel_launch(void* const* d_in, const int* in_sizes, int n_in,
                              void* d_out, int out_size, void* d_ws, size_t ws_size,
                              hipStream_t stream){
    const float* feat_src = (const float*)d_in[0];
    const float* feat_dst = (const float*)d_in[1];
    const int*   src_idx  = (const int*)d_in[2];
    const int*   dst_idx  = (const int*)d_in[3];
    const float* W_src = (const float*)d_in[4];
    const float* b_src = (const float*)d_in[5];
    const float* W_dst = (const float*)d_in[6];
    const float* b_dst = (const float*)d_in[7];
    const float* W_a1  = (const float*)d_in[8];
    const float* b_a1  = (const float*)d_in[9];
    const float* W_a2  = (const float*)d_in[10];
    const float* b_a2  = (const float*)d_in[11];
    const float* W_out = (const float*)d_in[12];
    const float* b_out = (const float*)d_in[13];
    const int n_src = in_sizes[0] / DD;
    const int n_dst = in_sizes[1] / DD;
    const int E = in_sizes[2];
    const int nchunks = (n_dst + SCHUNK - 1) / SCHUNK;

    // workspace layout (all 16B-aligned segments)
    char* p = (char*)d_ws;
    unsigned short* hs_h = (unsigned short*)p;  p += (size_t)n_src * DD * 2;
    unsigned short* hd_h = (unsigned short*)p;  p += (size_t)n_dst * DD * 2;
    unsigned short* wpack = (unsigned short*)p; p += 4 * 16384 * 2;
    float* s_w = (float*)p;                     p += (size_t)E * 4;
    unsigned int* pairs = (unsigned int*)p;     p += (size_t)E * 4;
    int* rank = (int*)p;                        p += (size_t)E * 4;
    int* deg = (int*)p;                         p += (size_t)n_dst * 4;
    int* part = (int*)p;                        p += 64 * 4;
    int* row_off = (int*)p;                     p += ((size_t)n_dst + 1) * 4;
    float* nf = (float*)d_out;

    const unsigned short* wa1p = wpack;
    const unsigned short* wsrc = wpack + 1 * 16384;
    const unsigned short* wdst = wpack + 2 * 16384;
    const unsigned short* wout = wpack + 3 * 16384;

    hipMemsetAsync(deg, 0, (size_t)n_dst * 4, stream);
    const int nhist = (E + 255) / 256;
    const int npack = (4 * 16384 + 255) / 256;
    hist_pack<<<nhist + npack, 256, 0, stream>>>(dst_idx, deg, rank, E, nhist,
                                                 W_a1, W_src, W_dst, W_out, wpack);
    scan1<<<nchunks, 1024, 0, stream>>>(deg, part, n_dst);
    scan2<<<nchunks, 1024, 0, stream>>>(deg, part, row_off, n_dst, nchunks);
    const int nsc = (E + 255) / 256;
    const int g1 = (n_src + 127) / 128;
    const int g2 = (n_dst + 127) / 128;
    scatter_lin2<<<nsc + g1 + g2, 256, 0, stream>>>(src_idx, dst_idx, row_off, rank,
                                                    pairs, E, nsc,
                                                    feat_src, wsrc, b_src, hs_h, n_src, g1,
                                                    feat_dst, wdst, b_dst, hd_h, n_dst);
    edge_score_mfma<<<(E + 255) / 256, 512, 0, stream>>>(hs_h, hd_h, pairs, wa1p, b_a1,
                                                         W_a2, b_a2, s_w, E);
    agg_lin<<<(n_dst + 7) / 8, 512, 0, stream>>>(hs_h, hd_h, row_off, pairs, s_w,
                                                 wout, b_out, nf, n_dst);
}